// Round 1
// baseline (4382.057 us; speedup 1.0000x reference)
//
#include <hip/hip_runtime.h>
#include <hip/hip_bf16.h>
#include <math.h>

#define N_NODES 50000
#define N_EDGES 1600000

struct GemmBatch {
  const float* W[4];
  const float* b[4];
  float* out[4];
};

// C[M,128] = A[M,K(lda)] @ W[K,128] + b ; one weight set per blockIdx.z
template<int K>
__global__ __launch_bounds__(256) void gemm128(const float* __restrict__ A, int lda, int M,
                                               GemmBatch gb) {
  const float* __restrict__ W    = gb.W[blockIdx.z];
  const float* __restrict__ bias = gb.b[blockIdx.z];
  float* __restrict__ out        = gb.out[blockIdx.z];
  __shared__ float xT[32][68];           // stride 68 floats = 272B -> 16B aligned rows
  int tid = threadIdx.x;
  int tc = tid & 31, tr = tid >> 5;      // tc: col group, tr: row group (0..7)
  int rbase = blockIdx.x * 64;
  float acc[8][4];
  #pragma unroll
  for (int i = 0; i < 8; i++)
    #pragma unroll
    for (int m = 0; m < 4; m++) acc[i][m] = 0.f;

  for (int kc = 0; kc < K; kc += 32) {
    // stage A chunk transposed: xT[k][r]
    {
      int c = tid & 31, rg = tid >> 5;
      #pragma unroll
      for (int i = 0; i < 8; i++) {
        int r = rg * 8 + i;
        int row = rbase + r; if (row >= M) row = M - 1;   // clamp (safe read)
        xT[c][r] = A[(size_t)row * lda + kc + c];
      }
    }
    __syncthreads();
    #pragma unroll
    for (int k = 0; k < 32; k++) {
      float4 x0 = *(const float4*)&xT[k][tr * 8];
      float4 x1 = *(const float4*)&xT[k][tr * 8 + 4];
      float w[4];
      #pragma unroll
      for (int m = 0; m < 4; m++) w[m] = W[(size_t)(kc + k) * 128 + tc + 32 * m];
      float xr[8] = {x0.x, x0.y, x0.z, x0.w, x1.x, x1.y, x1.z, x1.w};
      #pragma unroll
      for (int i = 0; i < 8; i++)
        #pragma unroll
        for (int m = 0; m < 4; m++)
          acc[i][m] = fmaf(xr[i], w[m], acc[i][m]);
    }
    __syncthreads();
  }
  #pragma unroll
  for (int m = 0; m < 4; m++) {
    float bb = bias[tc + 32 * m];
    #pragma unroll
    for (int i = 0; i < 8; i++) {
      int row = rbase + tr * 8 + i;
      if (row < M) out[(size_t)row * 128 + tc + 32 * m] = acc[i][m] + bb;
    }
  }
}

// C[M,32] = A[M,K(lda)] @ W[K,32] + b   (edge input projection)
template<int K>
__global__ __launch_bounds__(256) void gemm32(const float* __restrict__ A, int lda, int M,
                                              const float* __restrict__ W,
                                              const float* __restrict__ bias,
                                              float* __restrict__ out) {
  __shared__ float xT[32][132];          // 528B rows -> 16B aligned
  int tid = threadIdx.x;
  int tc = tid & 31, tr = tid >> 5;      // tr 0..7 -> 16 rows each (128-row tile)
  int rbase = blockIdx.x * 128;
  float acc[16];
  #pragma unroll
  for (int i = 0; i < 16; i++) acc[i] = 0.f;

  for (int kc = 0; kc < K; kc += 32) {
    {
      int c = tid & 31, rg = tid >> 5;
      #pragma unroll
      for (int i = 0; i < 16; i++) {
        int r = rg * 16 + i;
        int row = rbase + r; if (row >= M) row = M - 1;
        xT[c][r] = A[(size_t)row * lda + kc + c];
      }
    }
    __syncthreads();
    #pragma unroll
    for (int k = 0; k < 32; k++) {
      float w = W[(size_t)(kc + k) * 32 + tc];
      #pragma unroll
      for (int u = 0; u < 4; u++) {
        float4 xv = *(const float4*)&xT[k][tr * 16 + 4 * u];
        acc[4*u+0] = fmaf(xv.x, w, acc[4*u+0]);
        acc[4*u+1] = fmaf(xv.y, w, acc[4*u+1]);
        acc[4*u+2] = fmaf(xv.z, w, acc[4*u+2]);
        acc[4*u+3] = fmaf(xv.w, w, acc[4*u+3]);
      }
    }
    __syncthreads();
  }
  float bb = bias[tc];
  #pragma unroll
  for (int i = 0; i < 16; i++) {
    int row = rbase + tr * 16 + i;
    if (row < M) out[(size_t)row * 32 + tc] = acc[i] + bb;
  }
}

// per edge: el = e_row @ Wed + bed ; gate = sigmoid(k[dst]+q[src]+el);
// atomicAdd(agg[dst], gate * v[src])
__global__ __launch_bounds__(256) void edge_kernel(const float* __restrict__ e,
    const int* __restrict__ src, const int* __restrict__ dst,
    const float* __restrict__ kf, const float* __restrict__ qf, const float* __restrict__ vf,
    const float* __restrict__ Wed, const float* __restrict__ bed,
    float* __restrict__ agg, int nE) {
  __shared__ float wlds[32 * 128];       // 16 KB
  int tid = threadIdx.x;
  #pragma unroll
  for (int t = 0; t < 16; t++) wlds[tid + 256 * t] = Wed[tid + 256 * t];
  __syncthreads();
  int j = tid & 127;                     // output column
  int sub = tid >> 7;                    // which of 2 edges this half-block owns
  float bj = bed[j];
  for (int eid = blockIdx.x * 2 + sub; eid < nE; eid += gridDim.x * 2) {
    int s = src[eid], d = dst[eid];
    const float4* er = (const float4*)(e + (size_t)eid * 32);
    float el = bj;
    #pragma unroll
    for (int t = 0; t < 8; t++) {
      float4 ev = er[t];
      el = fmaf(ev.x, wlds[(4*t+0)*128 + j], el);
      el = fmaf(ev.y, wlds[(4*t+1)*128 + j], el);
      el = fmaf(ev.z, wlds[(4*t+2)*128 + j], el);
      el = fmaf(ev.w, wlds[(4*t+3)*128 + j], el);
    }
    float kd = kf[(size_t)d * 128 + j];
    float qs = qf[(size_t)s * 128 + j];
    float vs = vf[(size_t)s * 128 + j];
    float t  = kd + qs + el;
    float u  = __expf(-t);
    float g  = __builtin_amdgcn_rcpf(1.0f + u);
    atomicAdd(&agg[(size_t)d * 128 + j], g * vs);
  }
}

// LayerNorm per row of 128, wave per row; writes into hid slice (ldo=384)
__global__ __launch_bounds__(256) void ln_kernel(const float* __restrict__ agg,
    const float* __restrict__ g, const float* __restrict__ b,
    float* __restrict__ out, int ldo, int M) {
  int tid = threadIdx.x;
  int lane = tid & 63;
  int row = blockIdx.x * 4 + (tid >> 6);
  if (row >= M) return;
  float a0 = agg[(size_t)row * 128 + lane];
  float a1 = agg[(size_t)row * 128 + 64 + lane];
  float s = a0 + a1, ss = a0 * a0 + a1 * a1;
  #pragma unroll
  for (int off = 32; off; off >>= 1) {
    s  += __shfl_xor(s, off);
    ss += __shfl_xor(ss, off);
  }
  float mean = s * (1.f / 128.f);
  float var  = ss * (1.f / 128.f) - mean * mean;
  float rstd = rsqrtf(var + 1e-5f);
  float h0 = (a0 - mean) * rstd * g[lane] + b[lane];
  float h1 = (a1 - mean) * rstd * g[lane + 64] + b[lane + 64];
  out[(size_t)row * ldo + lane]      = h0;
  out[(size_t)row * ldo + lane + 64] = h1;
}

extern "C" void kernel_launch(void* const* d_in, const int* in_sizes, int n_in,
                              void* d_out, int out_size, void* d_ws, size_t ws_size,
                              hipStream_t stream) {
  const float* nf  = (const float*)d_in[0];
  const int*   ei  = (const int*)  d_in[1];
  const float* ea  = (const float*)d_in[2];
  const float* Wn  = (const float*)d_in[3];
  const float* bn  = (const float*)d_in[4];
  const float* We  = (const float*)d_in[5];
  const float* be  = (const float*)d_in[6];
  const float* Wk  = (const float*)d_in[7];
  const float* bk  = (const float*)d_in[8];
  const float* Wq  = (const float*)d_in[9];
  const float* bq  = (const float*)d_in[10];
  const float* Wv  = (const float*)d_in[11];
  const float* bv  = (const float*)d_in[12];
  const float* Wed = (const float*)d_in[13];
  const float* bed = (const float*)d_in[14];
  const float* Wsk = (const float*)d_in[15];
  const float* cb  = (const float*)d_in[16];
  const float* lng = (const float*)d_in[17];
  const float* lnb = (const float*)d_in[18];
  const float* Wh  = (const float*)d_in[19];
  const float* bh  = (const float*)d_in[20];
  float* out = (float*)d_out;

  float* ws  = (float*)d_ws;
  float* x0  = ws;                                  // N*128
  float* e   = x0  + (size_t)N_NODES * 128;         // E*32
  float* kf  = e   + (size_t)N_EDGES * 32;          // N*128
  float* qf  = kf  + (size_t)N_NODES * 128;         // N*128
  float* vf  = qf  + (size_t)N_NODES * 128;         // N*128
  float* agg = vf  + (size_t)N_NODES * 128;         // N*128
  float* hid = agg + (size_t)N_NODES * 128;         // N*384

  const int* srcp = ei;
  const int* dstp = ei + N_EDGES;

  dim3 blk(256);
  int gN = (N_NODES + 63) / 64;

  { GemmBatch gb{}; gb.W[0] = Wn; gb.b[0] = bn; gb.out[0] = x0;
    gemm128<256><<<dim3(gN, 1, 1), blk, 0, stream>>>(nf, 256, N_NODES, gb); }

  gemm32<64><<<dim3(N_EDGES / 128), blk, 0, stream>>>(ea, 64, N_EDGES, We, be, e);

  const float* xcur = x0; int ldx = 128;
  for (int i = 0; i < 3; i++) {
    GemmBatch gb{};
    gb.W[0] = Wk  + (size_t)i * 128 * 128; gb.b[0] = bk + i * 128; gb.out[0] = kf;
    gb.W[1] = Wq  + (size_t)i * 128 * 128; gb.b[1] = bq + i * 128; gb.out[1] = qf;
    gb.W[2] = Wv  + (size_t)i * 128 * 128; gb.b[2] = bv + i * 128; gb.out[2] = vf;
    gb.W[3] = Wsk + (size_t)i * 128 * 128; gb.b[3] = cb + i * 128; gb.out[3] = agg;
    gemm128<128><<<dim3(gN, 1, 4), blk, 0, stream>>>(xcur, ldx, N_NODES, gb);

    edge_kernel<<<dim3(2048), blk, 0, stream>>>(e, srcp, dstp, kf, qf, vf,
        Wed + (size_t)i * 32 * 128, bed + i * 128, agg, N_EDGES);

    ln_kernel<<<dim3((N_NODES + 3) / 4), blk, 0, stream>>>(agg, lng + i * 128,
        lnb + i * 128, hid + i * 128, 384, N_NODES);

    xcur = hid + i * 128; ldx = 384;
  }

  { GemmBatch gb{}; gb.W[0] = Wh; gb.b[0] = bh; gb.out[0] = out;
    gemm128<384><<<dim3(gN, 1, 1), blk, 0, stream>>>(hid, 384, N_NODES, gb); }
}